// Round 4
// baseline (753.240 us; speedup 1.0000x reference)
//
#include <hip/hip_runtime.h>

// Problem constants (fixed by the reference): B=1
#define S_DIM 128
#define L_DIM 256
#define D_DIM 768
#define H_DIM 12
#define TD    2304            // 3*D
#define NROW  32768           // S*L
#define KDIM  768
#define LN_EPS 1e-5f

typedef unsigned short u16;
typedef unsigned int   u32;
typedef _Float16 f16;
typedef _Float16 f16x8 __attribute__((ext_vector_type(8)));
typedef _Float16 f16x4 __attribute__((ext_vector_type(4)));
typedef float    f32x4 __attribute__((ext_vector_type(4)));

// Workspace layout (bytes), total 224,133,120:
//  region R (151 MB, off 0) is time-multiplexed:
//    row phase : qt f16[H][L][8192] 50.33M | kt same | vt f16[H][8192][256] 50.33M
//                (qt slot is reused as rout_h f16[NROW][D] after row_logits)
//    col phase : p  f16[NROW][TD]  151 MB   (GEMM2 overwrites; qt/kt/vt dead)
#define WS_QT_OFF     0
#define WS_KT_OFF     50331648
#define WS_VT_OFF     100663296
#define WS_P_OFF      0
#define WS_LPART_OFF  150994944
#define WS_PT_OFF     163577856
#define WS_XH_OFF     166723584
#define WS_WRH_OFF    217055232
#define WS_WCH_OFF    220594176

// fp16 staging (NOT bf16): row logits accumulate K=8192 products; bf16 failed
// absmax. fp16 passes at 0.047 with fp16-input MFMA, fp32 accum.
__device__ __forceinline__ void gload_lds16(const void* g, void* l) {
    __builtin_amdgcn_global_load_lds((const __attribute__((address_space(1))) void*)g,
                                     (__attribute__((address_space(3))) void*)l, 16, 0, 0);
}

// ---------------------------------------------------------------------------
// f32 -> f16 convert, 4 elems/thread, grid sized exactly (n % 1024 == 0).
// ---------------------------------------------------------------------------
__global__ __launch_bounds__(256)
void cvt_f32_f16(const float* __restrict__ in, f16* __restrict__ out)
{
    int i = blockIdx.x * 256 + threadIdx.x;
    float4 v = ((const float4*)in)[i];
    f16x4 o; o.x = (f16)v.x; o.y = (f16)v.y; o.z = (f16)v.z; o.w = (f16)v.w;
    ((f16x4*)out)[i] = o;
}

// ---------------------------------------------------------------------------
// MFMA GEMM core (m97 pattern, used by logits/PV): 128x128 tile, BK=32,
// 256 thr = 4 waves (2x2 of 64x64), each wave 4x4 of mfma_f32_16x16x32_f16.
// ---------------------------------------------------------------------------
#define MFMA_PROLOG(KROW)                                                     \
    __shared__ f16 As[128 * 32];                                              \
    __shared__ f16 Bs[128 * 32];                                              \
    const int tid  = threadIdx.x;                                             \
    const int lane = tid & 63;                                                \
    const int w    = tid >> 6;                                                \
    const int wr   = (w >> 1) * 64;                                           \
    const int wc   = (w & 1) * 64;                                            \
    const int lm   = lane & 15;                                               \
    const int q    = lane >> 4;                                               \
    size_t soff[2];                                                           \
    int    ldsc[2];                                                           \
    _Pragma("unroll")                                                         \
    for (int t = 0; t < 2; ++t) {                                             \
        int c  = w * 128 + t * 64 + lane;                                     \
        int m  = c >> 2;                                                      \
        int gj = (c & 3) ^ ((m >> 1) & 3);                                    \
        soff[t] = (size_t)m * (KROW) + gj * 8;                                \
        ldsc[t] = (w * 128 + t * 64) * 8;                                     \
    }                                                                         \
    int chA[4], chB[4];                                                       \
    _Pragma("unroll")                                                         \
    for (int t = 0; t < 4; ++t) {                                             \
        int ma = wr + t * 16 + lm;                                            \
        chA[t] = ma * 4 + (q ^ ((ma >> 1) & 3));                              \
        int mb = wc + t * 16 + lm;                                            \
        chB[t] = mb * 4 + (q ^ ((mb >> 1) & 3));                              \
    }                                                                         \
    f32x4 acc[4][4];                                                          \
    _Pragma("unroll")                                                         \
    for (int i = 0; i < 4; ++i)                                               \
        _Pragma("unroll")                                                     \
        for (int j = 0; j < 4; ++j) acc[i][j] = (f32x4)0.f;

#define MFMA_KLOOP(baseA, baseB, KLEN)                                        \
    for (int k0 = 0; k0 < (KLEN); k0 += 32) {                                 \
        _Pragma("unroll")                                                     \
        for (int t = 0; t < 2; ++t) {                                         \
            gload_lds16((baseA) + soff[t] + k0, &As[ldsc[t]]);                \
            gload_lds16((baseB) + soff[t] + k0, &Bs[ldsc[t]]);                \
        }                                                                     \
        __syncthreads();                                                      \
        f16x8 af[4], bf[4];                                                   \
        _Pragma("unroll")                                                     \
        for (int t = 0; t < 4; ++t) af[t] = *(const f16x8*)&As[chA[t] * 8];   \
        _Pragma("unroll")                                                     \
        for (int t = 0; t < 4; ++t) bf[t] = *(const f16x8*)&Bs[chB[t] * 8];   \
        _Pragma("unroll")                                                     \
        for (int mt = 0; mt < 4; ++mt)                                        \
            _Pragma("unroll")                                                 \
            for (int nt = 0; nt < 4; ++nt)                                    \
                acc[mt][nt] = __builtin_amdgcn_mfma_f32_16x16x32_f16(         \
                    af[mt], bf[nt], acc[mt][nt], 0, 0, 0);                    \
        __syncthreads();                                                      \
    }

// ---------------------------------------------------------------------------
// P8: 256x256-tile GEMM, faithful m201 8-phase schedule (T2+T3+T4+T5).
// BK=64, 512 thr = 8 waves (2M x 4N), wave tile 128x64 = 8x4 frags.
// Double-buffered LDS (4 x 32 KB = 128 KB). Per K-tile: 4 phases of
//   { ds_read subtile (8 or 4 b128) | issue stage (ph0: A(t+1) 4 gloads,
//     ph1: B(t+1) 4 gloads) | sched_barrier | s_barrier | lgkmcnt(0) +
//     sched_barrier (rule #18) | setprio(1) | 16 MFMA | setprio(0) |
//     s_barrier }.
// MFMA quadrants: (mt0-3,ks0) (mt4-7,ks0) (mt0-3,ks1) (mt4-7,ks1); bf frags
// live across phase pairs. ONE vmcnt(0) per tile boundary: all outstanding
// loads are tile-(t+1) data issued >=2.5 phases (~1000 cyc) earlier, so the
// drain is latency-covered (R2 drained with ~0 cover; R3 had no phases --
// m196's measured -7..-27% coarse-variant trap).
// 2-buffer safety: tile t stages ONLY buf[(t+1)%2], whose last reads
// completed before tile t began (program-order issue after read-complete).
// Swizzle: chunk j stored at j ^ (row&7), pre-swizzled source, XOR on read
// (0 bank conflicts, proven rounds 1-3).
// ---------------------------------------------------------------------------
#define P8_PROLOG()                                                           \
    __shared__ f16 As0[256 * 64];                                             \
    __shared__ f16 Bs0[256 * 64];                                             \
    __shared__ f16 As1[256 * 64];                                             \
    __shared__ f16 Bs1[256 * 64];                                             \
    const int tid  = threadIdx.x;                                             \
    const int lane = tid & 63;                                                \
    const int w    = tid >> 6;                                                \
    const int wr   = (w >> 2) * 128;                                          \
    const int wc   = (w & 3) * 64;                                            \
    const int lm   = lane & 15;                                               \
    const int q    = lane >> 4;                                               \
    size_t soff[4];                                                           \
    int    ldsb[4];                                                           \
    _Pragma("unroll")                                                         \
    for (int i = 0; i < 4; ++i) {                                             \
        int c = i * 512 + tid;                                                \
        int r = c >> 3;                                                       \
        int j = (c & 7) ^ (r & 7);                                            \
        soff[i] = (size_t)r * KDIM + j * 8;                                   \
        ldsb[i] = (i * 512 + w * 64) * 8;                                     \
    }                                                                         \
    f32x4 acc[8][4];                                                          \
    _Pragma("unroll")                                                         \
    for (int i = 0; i < 8; ++i)                                               \
        _Pragma("unroll")                                                     \
        for (int j = 0; j < 4; ++j) acc[i][j] = (f32x4)0.f;

#define P8_STAGE(Dst, basep, kk)                                              \
    _Pragma("unroll")                                                         \
    for (int i = 0; i < 4; ++i)                                               \
        gload_lds16((basep) + soff[i] + (size_t)(kk) * 64, &Dst[ldsb[i]]);

#define P8_FRAG(buf, row, ks)                                                 \
    (*(const f16x8*)&buf[(size_t)(row) * 64 +                                 \
                         ((((ks) * 4 + q) ^ ((row) & 7)) * 8)])

#define P8_SYNC_PRE()                                                         \
    __builtin_amdgcn_sched_barrier(0);                                        \
    __builtin_amdgcn_s_barrier();                                             \
    asm volatile("s_waitcnt lgkmcnt(0)" ::: "memory");                        \
    __builtin_amdgcn_sched_barrier(0);                                        \
    __builtin_amdgcn_s_setprio(1)

#define P8_SYNC_POST()                                                        \
    __builtin_amdgcn_s_setprio(0);                                            \
    __builtin_amdgcn_sched_barrier(0);                                        \
    __builtin_amdgcn_s_barrier()

#define P8_MFMA16(AF, MB)                                                     \
    _Pragma("unroll")                                                         \
    for (int mt = 0; mt < 4; ++mt)                                            \
        _Pragma("unroll")                                                     \
        for (int nt = 0; nt < 4; ++nt)                                        \
            acc[(MB) + mt][nt] = __builtin_amdgcn_mfma_f32_16x16x32_f16(      \
                AF[mt], bf[nt], acc[(MB) + mt][nt], 0, 0, 0);

#define P8_TILE(Ac, Bc, An, Bn, kn, PF)                                       \
  {                                                                           \
    f16x8 af[4], bf[4], ag[4];                                                \
    /* ---- phase 0: mt0-3 x ks0; stage A(t+1) ---- */                        \
    _Pragma("unroll")                                                         \
    for (int mt = 0; mt < 4; ++mt) af[mt] = P8_FRAG(Ac, wr + mt*16 + lm, 0);  \
    _Pragma("unroll")                                                         \
    for (int nt = 0; nt < 4; ++nt) bf[nt] = P8_FRAG(Bc, wc + nt*16 + lm, 0);  \
    if (PF) { P8_STAGE(An, baseA, kn) }                                       \
    P8_SYNC_PRE();                                                            \
    P8_MFMA16(af, 0)                                                          \
    P8_SYNC_POST();                                                           \
    /* ---- phase 1: mt4-7 x ks0 (bf live); stage B(t+1) ---- */              \
    _Pragma("unroll")                                                         \
    for (int mt = 0; mt < 4; ++mt)                                            \
        ag[mt] = P8_FRAG(Ac, wr + 64 + mt*16 + lm, 0);                        \
    if (PF) { P8_STAGE(Bn, baseB, kn) }                                       \
    P8_SYNC_PRE();                                                            \
    P8_MFMA16(ag, 4)                                                          \
    P8_SYNC_POST();                                                           \
    /* ---- phase 2: mt0-3 x ks1 ---- */                                      \
    _Pragma("unroll")                                                         \
    for (int mt = 0; mt < 4; ++mt) af[mt] = P8_FRAG(Ac, wr + mt*16 + lm, 1);  \
    _Pragma("unroll")                                                         \
    for (int nt = 0; nt < 4; ++nt) bf[nt] = P8_FRAG(Bc, wc + nt*16 + lm, 1);  \
    P8_SYNC_PRE();                                                            \
    P8_MFMA16(af, 0)                                                          \
    P8_SYNC_POST();                                                           \
    /* ---- phase 3: mt4-7 x ks1; boundary wait ---- */                       \
    _Pragma("unroll")                                                         \
    for (int mt = 0; mt < 4; ++mt)                                            \
        ag[mt] = P8_FRAG(Ac, wr + 64 + mt*16 + lm, 1);                        \
    P8_SYNC_PRE();                                                            \
    P8_MFMA16(ag, 4)                                                          \
    __builtin_amdgcn_s_setprio(0);                                            \
    __builtin_amdgcn_sched_barrier(0);                                        \
    if (PF) { asm volatile("s_waitcnt vmcnt(0)" ::: "memory"); }              \
    __builtin_amdgcn_s_barrier();                                             \
    __builtin_amdgcn_sched_barrier(0);                                        \
  }

// KDIM=768 -> 12 K-tiles, fully peeled (static buffer names, rule #20).
#define P8_KLOOP768()                                                         \
    P8_STAGE(As0, baseA, 0)                                                   \
    P8_STAGE(Bs0, baseB, 0)                                                   \
    asm volatile("s_waitcnt vmcnt(0)" ::: "memory");                          \
    __builtin_amdgcn_s_barrier();                                             \
    __builtin_amdgcn_sched_barrier(0);                                        \
    P8_TILE(As0, Bs0, As1, Bs1, 1,  1)                                        \
    P8_TILE(As1, Bs1, As0, Bs0, 2,  1)                                        \
    P8_TILE(As0, Bs0, As1, Bs1, 3,  1)                                        \
    P8_TILE(As1, Bs1, As0, Bs0, 4,  1)                                        \
    P8_TILE(As0, Bs0, As1, Bs1, 5,  1)                                        \
    P8_TILE(As1, Bs1, As0, Bs0, 6,  1)                                        \
    P8_TILE(As0, Bs0, As1, Bs1, 7,  1)                                        \
    P8_TILE(As1, Bs1, As0, Bs0, 8,  1)                                        \
    P8_TILE(As0, Bs0, As1, Bs1, 9,  1)                                        \
    P8_TILE(As1, Bs1, As0, Bs0, 10, 1)                                        \
    P8_TILE(As0, Bs0, As1, Bs1, 11, 1)                                        \
    P8_TILE(As1, Bs1, As0, Bs0, 0,  0)

// XCD-aware bijective swizzle: nwg = 9*128 = 1152 = 8*144 (divisible).
#define P8_SWIZZLE()                                                          \
    const int wg   = blockIdx.y * 9 + blockIdx.x;                             \
    const int swz  = (wg & 7) * 144 + (wg >> 3);                              \
    const int row0 = (swz / 9) * 256;                                         \
    const int col0 = (swz % 9) * 256;

// ---------------------------------------------------------------------------
// GEMM2 (col QKV): C = A*W^T + bias -> p f16 [NROW][TD]. grid (9,128) x512.
// ---------------------------------------------------------------------------
__global__ __launch_bounds__(512, 2)
void mfma_gemm_qkv(const f16* __restrict__ A, const f16* __restrict__ W,
                   const float* __restrict__ bias, f16* __restrict__ C)
{
    P8_SWIZZLE()
    P8_PROLOG()
    const f16* baseA = A + (size_t)row0 * KDIM;
    const f16* baseB = W + (size_t)col0 * KDIM;
    P8_KLOOP768()

    // C/D layout: col=lane&15, row=quad*4+reg
    float bv[4];
#pragma unroll
    for (int nt = 0; nt < 4; ++nt) bv[nt] = bias[col0 + wc + nt * 16 + lm];
#pragma unroll
    for (int mt = 0; mt < 8; ++mt) {
        int grow = row0 + wr + mt * 16 + q * 4;
#pragma unroll
        for (int nt = 0; nt < 4; ++nt) {
            int gcol = col0 + wc + nt * 16 + lm;
#pragma unroll
            for (int r = 0; r < 4; ++r)
                C[(size_t)(grow + r) * TD + gcol] = (f16)(acc[mt][nt][r] + bv[nt]);
        }
    }
}

// ---------------------------------------------------------------------------
// GEMM1 (row QKV): same core but scatter epilogue:
//   q -> qt[h][i][s*64+c], k -> kt[h][j][s*64+c], v -> vt[h][s*64+d][j].
// col0 tiles (256-wide) never straddle the 768/1536 q/k/v boundaries.
// ---------------------------------------------------------------------------
__global__ __launch_bounds__(512, 2)
void mfma_gemm_row(const f16* __restrict__ A, const f16* __restrict__ W,
                   const float* __restrict__ bias,
                   f16* __restrict__ qt, f16* __restrict__ kt,
                   f16* __restrict__ vt)
{
    P8_SWIZZLE()
    P8_PROLOG()
    const f16* baseA = A + (size_t)row0 * KDIM;
    const f16* baseB = W + (size_t)col0 * KDIM;
    P8_KLOOP768()

    if (col0 < 1536) {
        f16* dst = (col0 < 768) ? qt : kt;
        const int cbase = (col0 < 768) ? col0 : col0 - 768;
#pragma unroll
        for (int nt = 0; nt < 4; ++nt) {
            int gcol = cbase + wc + nt * 16 + lm;
            int h = gcol >> 6, c = gcol & 63;
            float b = bias[col0 + wc + nt * 16 + lm];
#pragma unroll
            for (int mt = 0; mt < 8; ++mt) {
                int n0 = row0 + wr + mt * 16 + q * 4;
#pragma unroll
                for (int r = 0; r < 4; ++r) {
                    int n = n0 + r;
                    int s = n >> 8, ii = n & 255;
                    dst[(((size_t)h * 256 + ii) * 128 + s) * 64 + c] =
                        (f16)(acc[mt][nt][r] + b);
                }
            }
        }
    } else {
#pragma unroll
        for (int nt = 0; nt < 4; ++nt) {
            int gcol = col0 + wc + nt * 16 + lm;
            int vcol = gcol - 1536;
            int h = vcol >> 6, d = vcol & 63;
            float b = bias[gcol];
#pragma unroll
            for (int mt = 0; mt < 8; ++mt) {
                int n0 = row0 + wr + mt * 16 + q * 4;
                int s = n0 >> 8, j0 = n0 & 255;   // r stays within one s
                f16x4 pack;
#pragma unroll
                for (int r = 0; r < 4; ++r) pack[r] = (f16)(acc[mt][nt][r] + b);
                *(f16x4*)&vt[((((size_t)h * 128 + s) * 64 + d) << 8) + j0] = pack;
            }
        }
    }
}

// ---------------------------------------------------------------------------
// Row logits via MFMA: split-K=4 partials. grid (2, 2, 48): z = h*4+sp.
// ---------------------------------------------------------------------------
__global__ __launch_bounds__(256)
void row_logits_mfma(const f16* __restrict__ qt, const f16* __restrict__ kt,
                     float* __restrict__ lpart)
{
    const int i0 = blockIdx.y * 128;
    const int j0 = blockIdx.x * 128;
    const int h  = blockIdx.z >> 2;
    const int sp = blockIdx.z & 3;
    MFMA_PROLOG(8192)
    const f16* baseA = qt + ((size_t)h * 256 + i0) * 8192 + sp * 2048;
    const f16* baseB = kt + ((size_t)h * 256 + j0) * 8192 + sp * 2048;
    MFMA_KLOOP(baseA, baseB, 2048)

    float* outp = lpart + (size_t)(sp * 12 + h) * 65536;
#pragma unroll
    for (int mt = 0; mt < 4; ++mt) {
        int grow = i0 + wr + mt * 16 + q * 4;
#pragma unroll
        for (int nt = 0; nt < 4; ++nt) {
            int gcol = j0 + wc + nt * 16 + lm;
#pragma unroll
            for (int r = 0; r < 4; ++r)
                outp[(size_t)(grow + r) * 256 + gcol] = acc[mt][nt][r];
        }
    }
}

// ---------------------------------------------------------------------------
// softmax over rows of 256, summing 4 split-K partials; probs out f16.
// ---------------------------------------------------------------------------
__global__ __launch_bounds__(256)
void softmax256_4(const float* __restrict__ lpart, f16* __restrict__ pt)
{
    __shared__ float red[256];
    const int t = threadIdx.x;
    const size_t idx = (size_t)blockIdx.x * 256 + t;
    const size_t P = (size_t)12 * 65536;
    float v = lpart[idx] + lpart[idx + P] + lpart[idx + 2*P] + lpart[idx + 3*P];
    red[t] = v; __syncthreads();
    for (int w = 128; w > 0; w >>= 1) { if (t < w) red[t] = fmaxf(red[t], red[t+w]); __syncthreads(); }
    float m = red[0];
    __syncthreads();
    float e = __expf(v - m);
    red[t] = e; __syncthreads();
    for (int w = 128; w > 0; w >>= 1) { if (t < w) red[t] += red[t+w]; __syncthreads(); }
    pt[idx] = (f16)(e / red[0]);
}

// ---------------------------------------------------------------------------
// Row PV via MFMA: per h, out[i,(s,d)] = sum_j pt[h][i][j] * vt[h][(s,d)][j].
// Output now f16 (rout_h, in the dead qt slot): halves PV-write + LN1-read
// HBM traffic. PV values are O(1) softmax-weighted averages -> f16 safe.
// ---------------------------------------------------------------------------
__global__ __launch_bounds__(256)
void row_pv_mfma(const f16* __restrict__ pt, const f16* __restrict__ vt,
                 f16* __restrict__ rout)
{
    const int n0t = blockIdx.x * 128;
    const int i0  = blockIdx.y * 128;
    const int h   = blockIdx.z;
    MFMA_PROLOG(256)
    const f16* baseA = pt + (size_t)h * 65536 + (size_t)i0 * 256;
    const f16* baseB = vt + ((size_t)h * 8192 + n0t) * 256;
    MFMA_KLOOP(baseA, baseB, 256)

#pragma unroll
    for (int mt = 0; mt < 4; ++mt) {
        int irow = i0 + wr + mt * 16 + q * 4;
#pragma unroll
        for (int nt = 0; nt < 4; ++nt) {
            int n = n0t + wc + nt * 16 + lm;
            int s = n >> 6, d = n & 63;
#pragma unroll
            for (int r = 0; r < 4; ++r)
                rout[(size_t)(s * 256 + irow + r) * D_DIM + h * 64 + d] =
                    (f16)acc[mt][nt][r];
        }
    }
}

// ---------------------------------------------------------------------------
// out1_h = f16(LN(x + r)); x f32, r f16. grid NROW, block 256.
// ---------------------------------------------------------------------------
__global__ __launch_bounds__(256)
void add_ln_out16(const float* __restrict__ x, const f16* __restrict__ r,
                  const float* __restrict__ g, const float* __restrict__ beta,
                  f16* __restrict__ out16)
{
    __shared__ float red[256];
    const int n = blockIdx.x, t = threadIdx.x;
    const float* xp = x + (size_t)n * D_DIM;
    const f16*   rp = r + (size_t)n * D_DIM;
    float v[3]; float s = 0.f;
#pragma unroll
    for (int e = 0; e < 3; ++e) { v[e] = xp[t + e*256] + (float)rp[t + e*256]; s += v[e]; }
    red[t] = s; __syncthreads();
    for (int w = 128; w > 0; w >>= 1) { if (t < w) red[t] += red[t+w]; __syncthreads(); }
    float mean = red[0] * (1.f/768.f);
    __syncthreads();
    float sq = 0.f;
#pragma unroll
    for (int e = 0; e < 3; ++e) { float d = v[e] - mean; sq += d*d; }
    red[t] = sq; __syncthreads();
    for (int w = 128; w > 0; w >>= 1) { if (t < w) red[t] += red[t+w]; __syncthreads(); }
    float rstd = rsqrtf(red[0] * (1.f/768.f) + LN_EPS);
#pragma unroll
    for (int e = 0; e < 3; ++e) {
        int idx = t + e*256;
        out16[(size_t)n * D_DIM + idx] = (f16)((v[e] - mean) * rstd * g[idx] + beta[idx]);
    }
}

// ---------------------------------------------------------------------------
// out = LN(x16 + r) f32, in place on r. grid NROW, block 256.
// ---------------------------------------------------------------------------
__global__ __launch_bounds__(256)
void add_ln_in16(const f16* __restrict__ x16, float* __restrict__ r,
                 const float* __restrict__ g, const float* __restrict__ beta)
{
    __shared__ float red[256];
    const int n = blockIdx.x, t = threadIdx.x;
    const f16*   xp = x16 + (size_t)n * D_DIM;
    float*       rp = r   + (size_t)n * D_DIM;
    float v[3]; float s = 0.f;
#pragma unroll
    for (int e = 0; e < 3; ++e) { v[e] = (float)xp[t + e*256] + rp[t + e*256]; s += v[e]; }
    red[t] = s; __syncthreads();
    for (int w = 128; w > 0; w >>= 1) { if (t < w) red[t] += red[t+w]; __syncthreads(); }
    float mean = red[0] * (1.f/768.f);
    __syncthreads();
    float sq = 0.f;
#pragma unroll
    for (int e = 0; e < 3; ++e) { float d = v[e] - mean; sq += d*d; }
    red[t] = sq; __syncthreads();
    for (int w = 128; w > 0; w >>= 1) { if (t < w) red[t] += red[t+w]; __syncthreads(); }
    float rstd = rsqrtf(red[0] * (1.f/768.f) + LN_EPS);
#pragma unroll
    for (int e = 0; e < 3; ++e) {
        int idx = t + e*256;
        rp[idx] = (v[e] - mean) * rstd * g[idx] + beta[idx];
    }
}

// ---------------------------------------------------------------------------
// Column attention via MFMA. One block per (l,h): grid (256, 12), 256 thr.
// ---------------------------------------------------------------------------
__global__ __launch_bounds__(256, 3)
void col_attn_mfma(const f16* __restrict__ p, float* __restrict__ cout)
{
    __shared__ char smem[54272];
    f16* Qs = (f16*)smem;             // [128][72]
    f16* Ks = (f16*)(smem + 18432);   // [128][72]
    f16* Ps = (f16*)smem;             // [128][136] overlay (after barrier)
    f16* Vt = (f16*)(smem + 36864);   // [64][136]

    const int tid  = threadIdx.x;
    const int lane = tid & 63;
    const int w    = tid >> 6;
    const int lm   = lane & 15;
    const int q    = lane >> 4;
    const int l = blockIdx.x, h = blockIdx.y;
    const int ib = w * 32;

    // ---- phase 1: stage Q,K row-major; V transposed into Vt[d][j]
    {
        const int r  = tid >> 1;          // s index 0..127
        const int hc = (tid & 1) * 32;    // c half
        const f16* rowp = p + (size_t)(r * 256 + l) * TD + h * 64 + hc;
#pragma unroll
        for (int cc = 0; cc < 4; ++cc)
            *(float4*)&Qs[r * 72 + hc + cc * 8] = *(const float4*)(rowp + cc * 8);
#pragma unroll
        for (int cc = 0; cc < 4; ++cc)
            *(float4*)&Ks[r * 72 + hc + cc * 8] = *(const float4*)(rowp + 768 + cc * 8);
#pragma unroll
        for (int cc = 0; cc < 4; ++cc) {
            union { float4 f; u16 u[8]; } vb;
            vb.f = *(const float4*)(rowp + 1536 + cc * 8);
#pragma unroll
            for (int e = 0; e < 8; ++e) {
                int d = hc + cc * 8 + e;
                ((u16*)Vt)[d * 136 + r] = vb.u[e];
            }
        }
    }
    __syncthreads();

    // ---- phase 2: S = Q K^T (wave tile 32x128: 2 mt x 8 nt x 2 ksteps)
    f32x4 acc[2][8];
#pragma unroll
    for (int mt = 0; mt < 2; ++mt)
#pragma unroll
        for (int nt = 0; nt < 8; ++nt) acc[mt][nt] = (f32x4)0.f;
#pragma unroll
    for (int ks = 0; ks < 2; ++ks) {
        f16x8 af[2];
#pragma unroll
        for (int mt = 0; mt < 2; ++mt)
            af[mt] = *(const f16x8*)&Qs[(ib + mt * 16 + lm) * 72 + ks * 32 + q * 8];
#pragma unroll
        for (int nt = 0; nt < 8; ++nt) {
            f16x8 bf = *(const f16x8*)&Ks[(nt * 16 + lm) * 72 + ks * 32 + q * 8];
#pragma unroll
            for (int mt = 0; mt < 2; ++mt)
                acc[mt][nt] = __builtin_amdgcn_mfma_f32_16x16x32_f16(
                    af[mt], bf, acc[mt][nt], 0, 0, 0);
        }
    }
    __syncthreads();   // all Qs/Ks frag reads done before Ps overlay writes

    // ---- phase 3: softmax over j in C-layout; write exp to Ps (f16)
    float inv_sum[2][4];
#pragma unroll
    for (int mt = 0; mt < 2; ++mt) {
#pragma unroll
        for (int r = 0; r < 4; ++r) {
            float m = acc[mt][0][r];
#pragma unroll
            for (int nt = 1; nt < 8; ++nt) m = fmaxf(m, acc[mt][nt][r]);
#pragma unroll
            for (int d = 1; d < 16; d <<= 1) m = fmaxf(m, __shfl_xor(m, d));
            float s = 0.f;
#pragma unroll
            for (int nt = 0; nt < 8; ++nt) {
                float e = __expf(acc[mt][nt][r] - m);
                acc[mt][nt][r] = e; s += e;
            }
#pragma unroll
            for (int d = 1; d < 16; d <<= 1) s += __shfl_xor(s, d);
            inv_sum[mt][r] = 1.f / s;
        }
        const int irow = ib + mt * 16 + q * 4;
#pragma unroll
        for (int nt = 0; nt < 8; ++nt) {
            const int jj = nt * 16 + lm;
#pragma unroll
            for (int r = 0; r < 4; ++r)
                Ps[(irow + r) * 136 + jj] = (f16)acc[mt][nt][r];
        }
    }
    __syncthreads();

    // ---- phase 4: O = P~ V (wave tile 32x64: 2 mt x 4 nt x 4 ksteps)
    f32x4 acc2[2][4];
#pragma unroll
    for (int mt = 0; mt < 2; ++mt)
#pragma unroll
        for (int nt = 0; nt < 4; ++nt) acc2[mt][nt] = (f32x4)0.f;
#pragma unroll
    for (int ks = 0; ks < 4; ++ks) {
        f16x8 pf[2];
#pragma unroll
        for (int mt = 0; mt < 2; ++mt)
            pf[mt] = *(const f16x8*)&Ps[(ib + mt * 16 + lm) * 136 + ks * 32 + q * 8];
#pragma unroll
        for (int nt = 0; nt < 4; ++nt) {
            f16x8 vf = *(const f16x8*)&Vt[(nt * 16 + lm) * 136 + ks * 32 + q * 8];
#pragma unroll
            for (int mt = 0; mt < 2; ++mt)
                acc2[mt][nt] = __builtin_amdgcn_mfma_f32_16x16x32_f16(
                    pf[mt], vf, acc2[mt][nt], 0, 0, 0);
        }
    }

    // ---- epilogue: apply deferred 1/sum, write f32
#pragma unroll
    for (int mt = 0; mt < 2; ++mt) {
        const int irow = ib + mt * 16 + q * 4;
#pragma unroll
        for (int nt = 0; nt < 4; ++nt) {
            const int d = nt * 16 + lm;
#pragma unroll
            for (int r = 0; r < 4; ++r)
                cout[(size_t)((irow + r) * 256 + l) * D_DIM + h * 64 + d] =
                    acc2[mt][nt][r] * inv_sum[mt][r];
        }
    }
}

// ---------------------------------------------------------------------------
extern "C" void kernel_launch(void* const* d_in, const int* in_sizes, int n_in,
                              void* d_out, int out_size, void* d_ws, size_t ws_size,
                              hipStream_t stream)
{
    const float* x     = (const float*)d_in[0];
    const float* w_row = (const float*)d_in[1];
    const float* b_row = (const float*)d_in[2];
    const float* w_col = (const float*)d_in[3];
    const float* b_col = (const float*)d_in[4];
    const float* g1    = (const float*)d_in[5];
    const float* be1   = (const float*)d_in[6];
    const float* g2    = (const float*)d_in[7];
    const float* be2   = (const float*)d_in[8];
    float* out = (float*)d_out;

    char* ws = (char*)d_ws;
    f16*   qt     = (f16*)(ws + WS_QT_OFF);
    f16*   kt     = (f16*)(ws + WS_KT_OFF);
    f16*   vt     = (f16*)(ws + WS_VT_OFF);
    f16*   p      = (f16*)(ws + WS_P_OFF);      // col phase, aliases qt/kt/vt
    float* lpart  = (float*)(ws + WS_LPART_OFF);
    f16*   pt     = (f16*)(ws + WS_PT_OFF);
    f16*   xh     = (f16*)(ws + WS_XH_OFF);     // also out1_h after step 5
    f16*   wrh    = (f16*)(ws + WS_WRH_OFF);
    f16*   wch    = (f16*)(ws + WS_WCH_OFF);
    f16*   rout_h = qt;                          // qt dead after row_logits

    // 0) f32 -> f16 converts
    cvt_f32_f16<<<NROW * D_DIM / 1024, 256, 0, stream>>>(x, xh);
    cvt_f32_f16<<<TD * D_DIM / 1024, 256, 0, stream>>>(w_row, wrh);
    cvt_f32_f16<<<TD * D_DIM / 1024, 256, 0, stream>>>(w_col, wch);
    // 1) row QKV projection (256^2 8-phase MFMA) -> qt/kt (K-major) + vt (j-major)
    mfma_gemm_row<<<dim3(9, 128), 512, 0, stream>>>(xh, wrh, b_row, qt, kt, vt);
    // 2) tied row logits (MFMA, split-K=4)
    row_logits_mfma<<<dim3(2, 2, 48), 256, 0, stream>>>(qt, kt, lpart);
    // 3) softmax over j (sums 4 partials) -> f16 probs
    softmax256_4<<<H_DIM * L_DIM, 256, 0, stream>>>(lpart, pt);
    // 4) row PV (MFMA) -> rout_h f16 (qt slot; qt dead after step 2)
    row_pv_mfma<<<dim3(64, 2, H_DIM), 256, 0, stream>>>(pt, vt, rout_h);
    // 5) out1_h = f16(LN(x + row_out))  (xh overwritten as out1_h)
    add_ln_out16<<<NROW, 256, 0, stream>>>(x, rout_h, g1, be1, xh);
    // 6) col QKV projection (256^2 8-phase MFMA) -> p (overwrites qt/kt/vt)
    mfma_gemm_qkv<<<dim3(9, 128), 512, 0, stream>>>(xh, wch, b_col, p);
    // 7) column attention (MFMA) -> d_out (scratch)
    col_attn_mfma<<<dim3(L_DIM, H_DIM), 256, 0, stream>>>(p, out);
    // 8) out = LN(out1_h + col_out), in place on d_out
    add_ln_in16<<<NROW, 256, 0, stream>>>(xh, out, g2, be2);
}